// Round 10
// baseline (380.467 us; speedup 1.0000x reference)
//
#include <hip/hip_runtime.h>
#include <hip/hip_fp16.h>

#define NODES 50000
#define EDGES 800000
#define DIM 128
#define EPS_BN 1e-5f
#define SCAN_B 1024
#define SCAN_NB ((NODES + SCAN_B - 1) / SCAN_B)   // 49
#define PG_NB ((NODES + 63) / 64)                 // 782 fused pull+gemm blocks
#define NCH 64                                    // edge chunks
#define CHE (EDGES / NCH)                         // 12500 edges/chunk
#define NR 4                                      // node ranges
#define RNG (NODES / NR)                          // 12500 nodes/range

typedef _Float16 half8 __attribute__((ext_vector_type(8)));
typedef float floatx4 __attribute__((ext_vector_type(4)));

union H8 { half8 v; __half2 h2[4]; };

// ---------------- pass 1: partial LDS histograms (no global atomics) ----------------
__global__ __launch_bounds__(256) void hist_part_kernel(const int* __restrict__ src,
                                                        const int* __restrict__ dst,
                                                        unsigned short* __restrict__ Psrc,
                                                        unsigned short* __restrict__ Pdst) {
    __shared__ int h[RNG];   // 50 KB
    int chunk = blockIdx.x & (NCH - 1);
    int range = blockIdx.x >> 6;
    const int* arr = blockIdx.y ? dst : src;
    unsigned short* P = blockIdx.y ? Pdst : Psrc;
    int base = range * RNG;
    for (int i = threadIdx.x; i < RNG; i += 256) h[i] = 0;
    __syncthreads();
    int e0 = chunk * CHE;
    for (int e = e0 + threadIdx.x; e < e0 + CHE; e += 256) {
        unsigned r = (unsigned)(arr[e] - base);
        if (r < (unsigned)RNG) atomicAdd(&h[r], 1);
    }
    __syncthreads();
    for (int i = threadIdx.x; i < RNG; i += 256)
        P[(size_t)chunk * NODES + base + i] = (unsigned short)h[i];
}

// ---------------- pass 2: degrees + per-chunk scan bases ----------------
__global__ __launch_bounds__(256) void combine_kernel(const unsigned short* __restrict__ Psrc,
                                                      unsigned short* __restrict__ Pdst,
                                                      int* __restrict__ cnt_in,
                                                      float* __restrict__ dn_out,
                                                      float* __restrict__ sdeg,
                                                      float* __restrict__ dn_in) {
    int v = blockIdx.x * 256 + threadIdx.x;
    if (v >= NODES) return;
    int s = 0;
    #pragma unroll 8
    for (int j = 0; j < NCH; ++j) s += Psrc[(size_t)j * NODES + v];
    float fs = (float)max(s, 1);
    dn_out[v] = rsqrtf(fs);
    sdeg[v] = sqrtf(fs);
    int run = 0;
    #pragma unroll 8
    for (int j = 0; j < NCH; ++j) {
        int t = Pdst[(size_t)j * NODES + v];
        Pdst[(size_t)j * NODES + v] = (unsigned short)run;
        run += t;
    }
    cnt_in[v] = run;
    dn_in[v] = rsqrtf((float)max(run, 1));
}

// ---------------- row_ptr scan over cnt_in ----------------
__global__ __launch_bounds__(SCAN_B) void scan_p1_kernel(const int* __restrict__ cnt,
                                                         int* __restrict__ row_ptr,
                                                         int* __restrict__ blk_sums) {
    __shared__ int sm[SCAN_B];
    int t = threadIdx.x;
    int idx = blockIdx.x * SCAN_B + t;
    int v = (idx < NODES) ? cnt[idx] : 0;
    sm[t] = v;
    __syncthreads();
    #pragma unroll
    for (int off = 1; off < SCAN_B; off <<= 1) {
        int u = (t >= off) ? sm[t - off] : 0;
        __syncthreads();
        sm[t] += u;
        __syncthreads();
    }
    if (idx < NODES) row_ptr[idx] = sm[t] - v;
    if (t == SCAN_B - 1) blk_sums[blockIdx.x] = sm[t];
}

__global__ __launch_bounds__(SCAN_B) void scan_p3_kernel(int* __restrict__ row_ptr,
                                                         const int* __restrict__ blk_sums) {
    __shared__ int soff;
    int t = threadIdx.x;
    if (t < 64) {
        int v = (t < blockIdx.x) ? blk_sums[t] : 0;
        #pragma unroll
        for (int off = 32; off > 0; off >>= 1) v += __shfl_xor(v, off);
        if (t == 0) soff = v;
    }
    __syncthreads();
    int idx = blockIdx.x * SCAN_B + t;
    if (idx < NODES) row_ptr[idx] += soff;
    if (idx == 0) row_ptr[NODES] = EDGES;
}

// ---------------- pass 3: CSR fill via local re-histogram ----------------
__global__ __launch_bounds__(256) void fill_kernel(const int* __restrict__ src,
                                                   const int* __restrict__ dst,
                                                   const int* __restrict__ row_ptr,
                                                   const unsigned short* __restrict__ Pdst,
                                                   int* __restrict__ csr_src) {
    __shared__ int h[RNG];   // 50 KB
    int chunk = blockIdx.x & (NCH - 1);
    int range = blockIdx.x >> 6;
    int base = range * RNG;
    for (int i = threadIdx.x; i < RNG; i += 256) h[i] = 0;
    __syncthreads();
    int e0 = chunk * CHE;
    const unsigned short* Pj = Pdst + (size_t)chunk * NODES;
    for (int e = e0 + threadIdx.x; e < e0 + CHE; e += 256) {
        int d = dst[e];
        unsigned r = (unsigned)(d - base);
        if (r < (unsigned)RNG) {
            int local = atomicAdd(&h[r], 1);   // LDS atomic only
            csr_src[row_ptr[d] + (int)Pj[d] + local] = src[e];
        }
    }
}

// ---------------- W1+W2 fp32 -> fp16 transposed; also zero p2 ----------------
__global__ __launch_bounds__(256) void w2h_kernel(const float* __restrict__ W1,
                                                  const float* __restrict__ W2,
                                                  __half* __restrict__ WhT1,
                                                  __half* __restrict__ WhT2,
                                                  float* __restrict__ p2) {
    int idx = blockIdx.x * 256 + threadIdx.x;   // 32768 total
    if (blockIdx.x < 32) p2[blockIdx.x * 256 + threadIdx.x] = 0.f;
    const float* W = (idx < 16384) ? W1 : W2;
    __half* D = (idx < 16384) ? WhT1 : WhT2;
    int i = idx & 16383;
    int n = i >> 7;
    int k = i & 127;
    D[i] = __float2half(W[k * DIM + n]);        // D[n][k] = W[k][n]
}

// ---------------- prescale to fp16 ----------------
__global__ __launch_bounds__(256) void prescale_kernel(const float* __restrict__ x,
                                                       const float* __restrict__ dn_out,
                                                       __half* __restrict__ hs) {
    int idx = blockIdx.x * 256 + threadIdx.x;   // over N*16
    if (idx >= NODES * 16) return;
    int row = idx >> 4;
    int c8 = (idx & 15) * 8;
    float sc = dn_out[row];
    const float* xp = x + (size_t)row * DIM + c8;
    float4 v0 = *(const float4*)xp;
    float4 v1 = *(const float4*)(xp + 4);
    H8 u;
    u.h2[0] = __floats2half2_rn(v0.x * sc, v0.y * sc);
    u.h2[1] = __floats2half2_rn(v0.z * sc, v0.w * sc);
    u.h2[2] = __floats2half2_rn(v1.x * sc, v1.y * sc);
    u.h2[3] = __floats2half2_rn(v1.z * sc, v1.w * sc);
    *(half8*)((char*)hs + ((size_t)row * DIM + c8) * 2) = u.v;
}

// ---------------- fused pull + MFMA GEMM + stats atomics ----------------
// 64 rows/block, 256 threads = 4 waves. Phase A: each wave aggregates 16 nodes
// into LDS (fp16, 272B row stride). Phase B: MFMA vs LDS-staged WhT.
// Epilogue: hraw fp16 out + per-block column stats atomicAdd into p2[blk&31].
__device__ __forceinline__ void acc_h8(half8 raw, float* a) {
    H8 u; u.v = raw;
    #pragma unroll
    for (int k = 0; k < 4; ++k) {
        float2 f = __half22float2(u.h2[k]);
        a[2 * k] += f.x;
        a[2 * k + 1] += f.y;
    }
}

__global__ __launch_bounds__(256) void pullgemm_kernel(const __half* __restrict__ hs,
                                                       const int* __restrict__ row_ptr,
                                                       const int* __restrict__ csr_src,
                                                       const float* __restrict__ dn_in,
                                                       const __half* __restrict__ WhT,
                                                       const float* __restrict__ bias,
                                                       __half* __restrict__ hraw,
                                                       float* __restrict__ p2) {
    __shared__ float smem[13056];                 // 52224 B
    __half* wl = (__half*)smem;                   // WhT tile: 128 rows x 272 B
    char* at = (char*)smem + 34816;               // A tile: 64 rows x 272 B
    float* ps = (float*)at;                       // stats scratch (aliased after MFMA)

    int t = threadIdx.x;

    // stage WhT
    #pragma unroll
    for (int i = 0; i < 8; ++i) {
        int cch = t + 256 * i;
        int n = cch >> 4;
        int ch = cch & 15;
        *(float4*)((char*)wl + n * 272 + ch * 16) =
            *(const float4*)((const char*)WhT + n * 256 + ch * 16);
    }

    int w = t >> 6;
    int lane = t & 63;
    int q = lane >> 4;        // edge slot 0..3
    int c = lane & 15;        // 16-B chunk
    int r0 = blockIdx.x * 64;
    const char* base = (const char*)hs;

    // Phase A: wave w aggregates nodes r0 + w*16 + i
    for (int i = 0; i < 16; ++i) {
        int node = r0 + w * 16 + i;
        char* arow = at + (w * 16 + i) * 272 + c * 16;
        if (node < NODES) {
            int beg = row_ptr[node];
            int end = row_ptr[node + 1];
            float a[8];
            #pragma unroll
            for (int k = 0; k < 8; ++k) a[k] = 0.f;
            int eb = beg;
            for (; eb + 8 <= end; eb += 8) {
                int s0 = csr_src[eb + q];
                int s1 = csr_src[eb + 4 + q];
                half8 v0 = *(const half8*)(base + (size_t)s0 * 256 + c * 16);
                half8 v1 = *(const half8*)(base + (size_t)s1 * 256 + c * 16);
                acc_h8(v0, a);
                acc_h8(v1, a);
            }
            for (; eb + 4 <= end; eb += 4) {
                int s0 = csr_src[eb + q];
                half8 v0 = *(const half8*)(base + (size_t)s0 * 256 + c * 16);
                acc_h8(v0, a);
            }
            if (eb + q < end) {
                int s0 = csr_src[eb + q];
                half8 v0 = *(const half8*)(base + (size_t)s0 * 256 + c * 16);
                acc_h8(v0, a);
            }
            #pragma unroll
            for (int k = 0; k < 8; ++k) a[k] += __shfl_xor(a[k], 32);
            #pragma unroll
            for (int k = 0; k < 8; ++k) a[k] += __shfl_xor(a[k], 16);
            if (lane < 16) {
                float sc = dn_in[node];
                H8 u;
                #pragma unroll
                for (int k = 0; k < 4; ++k)
                    u.h2[k] = __floats2half2_rn(a[2 * k] * sc, a[2 * k + 1] * sc);
                *(half8*)arow = u.v;
            }
        } else if (lane < 16) {
            H8 z;
            #pragma unroll
            for (int k = 0; k < 4; ++k) z.h2[k] = __floats2half2_rn(0.f, 0.f);
            *(half8*)arow = z.v;
        }
    }
    __syncthreads();

    // Phase B: MFMA
    int m = lane & 15;
    int quad = lane >> 4;
    half8 afrag[4];
    #pragma unroll
    for (int kt = 0; kt < 4; ++kt)
        afrag[kt] = *(const half8*)(at + (w * 16 + m) * 272 + kt * 64 + quad * 16);

    floatx4 acc[8];
    floatx4 zf = {0.f, 0.f, 0.f, 0.f};
    #pragma unroll
    for (int ct = 0; ct < 8; ++ct) acc[ct] = zf;

    #pragma unroll
    for (int kt = 0; kt < 4; ++kt) {
        #pragma unroll
        for (int ct = 0; ct < 8; ++ct) {
            half8 b = *(const half8*)((const char*)wl + (ct * 16 + m) * 272 + kt * 64 + quad * 16);
            acc[ct] = __builtin_amdgcn_mfma_f32_16x16x32_f16(afrag[kt], b, acc[ct], 0, 0, 0);
        }
    }
    __syncthreads();   // at tile fully consumed; reuse as ps

    int rr0 = r0 + w * 16;
    int g = w * 4 + quad;
    #pragma unroll
    for (int ct = 0; ct < 8; ++ct) {
        int col = ct * 16 + m;
        float bb = bias[col];
        float cs = 0.f, cq = 0.f;
        #pragma unroll
        for (int reg = 0; reg < 4; ++reg) {
            int row = rr0 + quad * 4 + reg;
            if (row < NODES) {
                float o = acc[ct][reg] + bb;
                hraw[(size_t)row * DIM + col] = __float2half(o);
                cs += o;
                cq += o * o;
            }
        }
        ps[g * 128 + col] = cs;
        ps[2048 + g * 128 + col] = cq;
    }
    __syncthreads();

    float* pslot = p2 + (blockIdx.x & 31) * 256;
    if (t < 128) {
        float s = 0.f;
        #pragma unroll
        for (int gg = 0; gg < 16; ++gg) s += ps[gg * 128 + t];
        atomicAdd(pslot + t, s);
    } else {
        int cc = t - 128;
        float s = 0.f;
        #pragma unroll
        for (int gg = 0; gg < 16; ++gg) s += ps[2048 + gg * 128 + cc];
        atomicAdd(pslot + 128 + cc, s);
    }
}

// ---------------- reduce p2 -> stats; re-zero p2 for next use ----------------
__global__ __launch_bounds__(256) void stats_s2_kernel(float* __restrict__ p2,
                                                       float* __restrict__ stats) {
    int t = threadIdx.x;
    float s = 0.f;
    #pragma unroll
    for (int b = 0; b < 32; ++b) s += p2[b * 256 + t];
    stats[t] = s;
    #pragma unroll
    for (int b = 0; b < 32; ++b) p2[b * 256 + t] = 0.f;
}

// ---------------- BN apply + ReLU (fp16 in) -> hs fp16 (scaled) only ----------------
__global__ __launch_bounds__(256) void bn_relu_scale_kernel(const __half* __restrict__ hraw,
                                                            __half* __restrict__ hs,
                                                            const float* __restrict__ stats,
                                                            const float* __restrict__ g,
                                                            const float* __restrict__ be,
                                                            const float* __restrict__ dn_out) {
    int idx = blockIdx.x * 256 + threadIdx.x;   // over N*16
    if (idx >= NODES * 16) return;
    int row = idx >> 4;
    int c8 = (idx & 15) * 8;
    const float invN = 1.0f / NODES;
    H8 u;
    u.v = *(const half8*)((const char*)hraw + ((size_t)row * DIM + c8) * 2);
    float o[8];
    #pragma unroll
    for (int k = 0; k < 4; ++k) {
        float2 f = __half22float2(u.h2[k]);
        o[2 * k] = f.x;
        o[2 * k + 1] = f.y;
    }
    #pragma unroll
    for (int j = 0; j < 8; ++j) {
        int cj = c8 + j;
        float mu = stats[cj] * invN;
        float var = stats[DIM + cj] * invN - mu * mu;
        float w = g[cj] * rsqrtf(var + EPS_BN);
        o[j] = fmaxf(w * (o[j] - mu) + be[cj], 0.f);
    }
    H8 us;
    float sc = dn_out[row];
    #pragma unroll
    for (int k = 0; k < 4; ++k)
        us.h2[k] = __floats2half2_rn(o[2 * k] * sc, o[2 * k + 1] * sc);
    *(half8*)((char*)hs + ((size_t)row * DIM + c8) * 2) = us.v;
}

// ---------------- BN + residual (reconstructed from hs) + ReLU -> out fp32 ----------
__global__ __launch_bounds__(256) void bn_res_relu_kernel(const __half* __restrict__ hraw,
                                                          const __half* __restrict__ hs,
                                                          const float* __restrict__ sdeg,
                                                          float* __restrict__ out,
                                                          const float* __restrict__ stats,
                                                          const float* __restrict__ g,
                                                          const float* __restrict__ be) {
    int idx = blockIdx.x * 256 + threadIdx.x;   // over N*16
    if (idx >= NODES * 16) return;
    int row = idx >> 4;
    int c8 = (idx & 15) * 8;
    const float invN = 1.0f / NODES;
    float sd = sdeg[row];
    H8 u, ur;
    u.v = *(const half8*)((const char*)hraw + ((size_t)row * DIM + c8) * 2);
    ur.v = *(const half8*)((const char*)hs + ((size_t)row * DIM + c8) * 2);
    float o[8], r[8];
    #pragma unroll
    for (int k = 0; k < 4; ++k) {
        float2 f = __half22float2(u.h2[k]);
        float2 fr = __half22float2(ur.h2[k]);
        o[2 * k] = f.x; o[2 * k + 1] = f.y;
        r[2 * k] = fr.x * sd; r[2 * k + 1] = fr.y * sd;
    }
    #pragma unroll
    for (int j = 0; j < 8; ++j) {
        int cj = c8 + j;
        float mu = stats[cj] * invN;
        float var = stats[DIM + cj] * invN - mu * mu;
        float w = g[cj] * rsqrtf(var + EPS_BN);
        o[j] = fmaxf(w * (o[j] - mu) + be[cj] + r[j], 0.f);
    }
    float* op = out + (size_t)row * DIM + c8;
    float4 o0 = {o[0], o[1], o[2], o[3]};
    float4 o1 = {o[4], o[5], o[6], o[7]};
    *(float4*)op = o0;
    *(float4*)(op + 4) = o1;
}

extern "C" void kernel_launch(void* const* d_in, const int* in_sizes, int n_in,
                              void* d_out, int out_size, void* d_ws, size_t ws_size,
                              hipStream_t stream) {
    const float* x      = (const float*)d_in[0];
    const int*   src    = (const int*)d_in[1];
    const int*   dst    = (const int*)d_in[2];
    const float* W1     = (const float*)d_in[3];
    const float* b1     = (const float*)d_in[4];
    const float* gamma1 = (const float*)d_in[5];
    const float* beta1  = (const float*)d_in[6];
    const float* W2     = (const float*)d_in[7];
    const float* b2     = (const float*)d_in[8];
    const float* gamma2 = (const float*)d_in[9];
    const float* beta2  = (const float*)d_in[10];
    float* out = (float*)d_out;

    char* wsc = (char*)d_ws;
    int*   cnt_in   = (int*)wsc;                     wsc += NODES * 4;
    float* dn_out   = (float*)wsc;                   wsc += NODES * 4;
    float* sdeg     = (float*)wsc;                   wsc += NODES * 4;
    float* dn_in    = (float*)wsc;                   wsc += NODES * 4;
    int*   row_ptr  = (int*)wsc;                     wsc += (NODES + 1) * 4;
    int*   csr_src  = (int*)wsc;                     wsc += EDGES * 4;
    float* stats    = (float*)wsc;                   wsc += 2 * DIM * 4;
    int*   blk_sums = (int*)wsc;                     wsc += 64 * 4;
    __half* WhT1    = (__half*)wsc;                  wsc += DIM * DIM * 2;
    __half* WhT2    = (__half*)wsc;                  wsc += DIM * DIM * 2;
    float* p2       = (float*)wsc;                   wsc += 32 * 256 * 4;
    unsigned short* Psrc = (unsigned short*)wsc;     wsc += (size_t)NCH * NODES * 2;
    unsigned short* Pdst = (unsigned short*)wsc;     wsc += (size_t)NCH * NODES * 2;
    __half* hs      = (__half*)wsc;                  wsc += (size_t)NODES * DIM * 2;
    __half* hraw    = (__half*)wsc;                  wsc += (size_t)NODES * DIM * 2;

    const int T = 256;
    const int grid_e16 = (NODES * 16 + T - 1) / T;

    // graph prep — LDS atomics only
    hist_part_kernel<<<dim3(NR * NCH, 2), T, 0, stream>>>(src, dst, Psrc, Pdst);
    combine_kernel<<<(NODES + T - 1) / T, T, 0, stream>>>(Psrc, Pdst, cnt_in, dn_out, sdeg, dn_in);
    scan_p1_kernel<<<SCAN_NB, SCAN_B, 0, stream>>>(cnt_in, row_ptr, blk_sums);
    scan_p3_kernel<<<SCAN_NB, SCAN_B, 0, stream>>>(row_ptr, blk_sums);
    fill_kernel<<<NR * NCH, T, 0, stream>>>(src, dst, row_ptr, Pdst, csr_src);

    // weight conversion + p2 zero
    w2h_kernel<<<128, T, 0, stream>>>(W1, W2, WhT1, WhT2, p2);

    // layer 1
    prescale_kernel<<<grid_e16, T, 0, stream>>>(x, dn_out, hs);
    pullgemm_kernel<<<PG_NB, T, 0, stream>>>(hs, row_ptr, csr_src, dn_in, WhT1, b1, hraw, p2);
    stats_s2_kernel<<<1, T, 0, stream>>>(p2, stats);
    bn_relu_scale_kernel<<<grid_e16, T, 0, stream>>>(hraw, hs, stats, gamma1, beta1, dn_out);

    // layer 2
    pullgemm_kernel<<<PG_NB, T, 0, stream>>>(hs, row_ptr, csr_src, dn_in, WhT2, b2, hraw, p2);
    stats_s2_kernel<<<1, T, 0, stream>>>(p2, stats);
    bn_res_relu_kernel<<<grid_e16, T, 0, stream>>>(hraw, hs, sdeg, out, stats, gamma2, beta2);
}

// Round 11
// 275.542 us; speedup vs baseline: 1.3808x; 1.3808x over previous
//
#include <hip/hip_runtime.h>
#include <hip/hip_fp16.h>

#define NODES 50000
#define EDGES 800000
#define DIM 128
#define EPS_BN 1e-5f
#define SCAN_B 1024
#define SCAN_NB ((NODES + SCAN_B - 1) / SCAN_B)   // 49
#define GEMM_NB ((NODES + 63) / 64)               // 782
#define NCH 64                                    // edge chunks
#define CHE (EDGES / NCH)                         // 12500 edges/chunk
#define NR 4                                      // node ranges
#define RNG (NODES / NR)                          // 12500 nodes/range

typedef _Float16 half8 __attribute__((ext_vector_type(8)));
typedef float floatx4 __attribute__((ext_vector_type(4)));

union H8 { half8 v; __half2 h2[4]; };

// ---------------- pass 1: partial LDS histograms (no global atomics) ----------------
__global__ __launch_bounds__(256) void hist_part_kernel(const int* __restrict__ src,
                                                        const int* __restrict__ dst,
                                                        unsigned short* __restrict__ Psrc,
                                                        unsigned short* __restrict__ Pdst) {
    __shared__ int h[RNG];   // 50 KB
    int chunk = blockIdx.x & (NCH - 1);
    int range = blockIdx.x >> 6;
    const int* arr = blockIdx.y ? dst : src;
    unsigned short* P = blockIdx.y ? Pdst : Psrc;
    int base = range * RNG;
    for (int i = threadIdx.x; i < RNG; i += 256) h[i] = 0;
    __syncthreads();
    int e0 = chunk * CHE;
    for (int e = e0 + threadIdx.x; e < e0 + CHE; e += 256) {
        unsigned r = (unsigned)(arr[e] - base);
        if (r < (unsigned)RNG) atomicAdd(&h[r], 1);
    }
    __syncthreads();
    for (int i = threadIdx.x; i < RNG; i += 256)
        P[(size_t)chunk * NODES + base + i] = (unsigned short)h[i];
}

// ---------------- pass 2: degrees + per-chunk scan bases ----------------
__global__ __launch_bounds__(256) void combine_kernel(const unsigned short* __restrict__ Psrc,
                                                      unsigned short* __restrict__ Pdst,
                                                      int* __restrict__ cnt_in,
                                                      float* __restrict__ dn_out,
                                                      float* __restrict__ sdeg,
                                                      float* __restrict__ dn_in) {
    int v = blockIdx.x * 256 + threadIdx.x;
    if (v >= NODES) return;
    int s = 0;
    #pragma unroll 8
    for (int j = 0; j < NCH; ++j) s += Psrc[(size_t)j * NODES + v];
    float fs = (float)max(s, 1);
    dn_out[v] = rsqrtf(fs);
    sdeg[v] = sqrtf(fs);
    int run = 0;
    #pragma unroll 8
    for (int j = 0; j < NCH; ++j) {
        int t = Pdst[(size_t)j * NODES + v];
        Pdst[(size_t)j * NODES + v] = (unsigned short)run;
        run += t;
    }
    cnt_in[v] = run;
    dn_in[v] = rsqrtf((float)max(run, 1));
}

// ---------------- row_ptr scan over cnt_in ----------------
__global__ __launch_bounds__(SCAN_B) void scan_p1_kernel(const int* __restrict__ cnt,
                                                         int* __restrict__ row_ptr,
                                                         int* __restrict__ blk_sums) {
    __shared__ int sm[SCAN_B];
    int t = threadIdx.x;
    int idx = blockIdx.x * SCAN_B + t;
    int v = (idx < NODES) ? cnt[idx] : 0;
    sm[t] = v;
    __syncthreads();
    #pragma unroll
    for (int off = 1; off < SCAN_B; off <<= 1) {
        int u = (t >= off) ? sm[t - off] : 0;
        __syncthreads();
        sm[t] += u;
        __syncthreads();
    }
    if (idx < NODES) row_ptr[idx] = sm[t] - v;
    if (t == SCAN_B - 1) blk_sums[blockIdx.x] = sm[t];
}

__global__ __launch_bounds__(SCAN_B) void scan_p3_kernel(int* __restrict__ row_ptr,
                                                         const int* __restrict__ blk_sums) {
    __shared__ int soff;
    int t = threadIdx.x;
    if (t < 64) {
        int v = (t < blockIdx.x) ? blk_sums[t] : 0;
        #pragma unroll
        for (int off = 32; off > 0; off >>= 1) v += __shfl_xor(v, off);
        if (t == 0) soff = v;
    }
    __syncthreads();
    int idx = blockIdx.x * SCAN_B + t;
    if (idx < NODES) row_ptr[idx] += soff;
    if (idx == 0) row_ptr[NODES] = EDGES;
}

// ---------------- pass 3: CSR fill via local re-histogram ----------------
__global__ __launch_bounds__(256) void fill_kernel(const int* __restrict__ src,
                                                   const int* __restrict__ dst,
                                                   const int* __restrict__ row_ptr,
                                                   const unsigned short* __restrict__ Pdst,
                                                   int* __restrict__ csr_src) {
    __shared__ int h[RNG];   // 50 KB
    int chunk = blockIdx.x & (NCH - 1);
    int range = blockIdx.x >> 6;
    int base = range * RNG;
    for (int i = threadIdx.x; i < RNG; i += 256) h[i] = 0;
    __syncthreads();
    int e0 = chunk * CHE;
    const unsigned short* Pj = Pdst + (size_t)chunk * NODES;
    for (int e = e0 + threadIdx.x; e < e0 + CHE; e += 256) {
        int d = dst[e];
        unsigned r = (unsigned)(d - base);
        if (r < (unsigned)RNG) {
            int local = atomicAdd(&h[r], 1);   // LDS atomic only
            csr_src[row_ptr[d] + (int)Pj[d] + local] = src[e];
        }
    }
}

// ---------------- W1+W2 fp32 -> fp16 transposed; also zero p2 ----------------
__global__ __launch_bounds__(256) void w2h_kernel(const float* __restrict__ W1,
                                                  const float* __restrict__ W2,
                                                  __half* __restrict__ WhT1,
                                                  __half* __restrict__ WhT2,
                                                  float* __restrict__ p2) {
    int idx = blockIdx.x * 256 + threadIdx.x;   // 32768 total
    if (blockIdx.x < 32) p2[blockIdx.x * 256 + threadIdx.x] = 0.f;
    const float* W = (idx < 16384) ? W1 : W2;
    __half* D = (idx < 16384) ? WhT1 : WhT2;
    int i = idx & 16383;
    int n = i >> 7;
    int k = i & 127;
    D[i] = __float2half(W[k * DIM + n]);        // D[n][k] = W[k][n]
}

// ---------------- prescale to fp16 ----------------
__global__ __launch_bounds__(256) void prescale_kernel(const float* __restrict__ x,
                                                       const float* __restrict__ dn_out,
                                                       __half* __restrict__ hs) {
    int idx = blockIdx.x * 256 + threadIdx.x;   // over N*16
    if (idx >= NODES * 16) return;
    int row = idx >> 4;
    int c8 = (idx & 15) * 8;
    float sc = dn_out[row];
    const float* xp = x + (size_t)row * DIM + c8;
    float4 v0 = *(const float4*)xp;
    float4 v1 = *(const float4*)(xp + 4);
    H8 u;
    u.h2[0] = __floats2half2_rn(v0.x * sc, v0.y * sc);
    u.h2[1] = __floats2half2_rn(v0.z * sc, v0.w * sc);
    u.h2[2] = __floats2half2_rn(v1.x * sc, v1.y * sc);
    u.h2[3] = __floats2half2_rn(v1.z * sc, v1.w * sc);
    *(half8*)((char*)hs + ((size_t)row * DIM + c8) * 2) = u.v;
}

// ---------------- pull: 1 wave/node, 16 lanes x 16 B per edge, 4 edge slots ---------
__device__ __forceinline__ void acc_h8(half8 raw, float* a) {
    H8 u; u.v = raw;
    #pragma unroll
    for (int k = 0; k < 4; ++k) {
        float2 f = __half22float2(u.h2[k]);
        a[2 * k] += f.x;
        a[2 * k + 1] += f.y;
    }
}

__global__ __launch_bounds__(256) void pull_kernel(const __half* __restrict__ hs,
                                                   const int* __restrict__ row_ptr,
                                                   const int* __restrict__ csr_src,
                                                   const float* __restrict__ dn_in,
                                                   __half* __restrict__ agg) {
    int wid = threadIdx.x >> 6;
    int node = blockIdx.x * 4 + wid;
    if (node >= NODES) return;
    int lane = threadIdx.x & 63;
    int q = lane >> 4;        // edge slot 0..3
    int c = lane & 15;        // 16-B chunk within row
    const char* base = (const char*)hs;
    int beg = row_ptr[node];
    int end = row_ptr[node + 1];
    float a[8];
    #pragma unroll
    for (int i = 0; i < 8; ++i) a[i] = 0.f;
    int eb = beg;
    for (; eb + 8 <= end; eb += 8) {
        int s0 = csr_src[eb + q];
        int s1 = csr_src[eb + 4 + q];
        half8 v0 = *(const half8*)(base + (size_t)s0 * 256 + c * 16);
        half8 v1 = *(const half8*)(base + (size_t)s1 * 256 + c * 16);
        acc_h8(v0, a);
        acc_h8(v1, a);
    }
    for (; eb + 4 <= end; eb += 4) {
        int s0 = csr_src[eb + q];
        half8 v0 = *(const half8*)(base + (size_t)s0 * 256 + c * 16);
        acc_h8(v0, a);
    }
    if (eb + q < end) {
        int s0 = csr_src[eb + q];
        half8 v0 = *(const half8*)(base + (size_t)s0 * 256 + c * 16);
        acc_h8(v0, a);
    }
    #pragma unroll
    for (int i = 0; i < 8; ++i) a[i] += __shfl_xor(a[i], 32);
    #pragma unroll
    for (int i = 0; i < 8; ++i) a[i] += __shfl_xor(a[i], 16);
    if (lane < 16) {
        float sc = dn_in[node];
        H8 u;
        #pragma unroll
        for (int k = 0; k < 4; ++k)
            u.h2[k] = __floats2half2_rn(a[2 * k] * sc, a[2 * k + 1] * sc);
        *(half8*)((char*)agg + (size_t)node * 256 + c * 16) = u.v;
    }
}

// ---------------- MFMA GEMM (fp16 in/out) + p2-atomic stats epilogue ----------------
__global__ __launch_bounds__(256) void gemm_mfma_kernel(const __half* __restrict__ A,
                                                        const __half* __restrict__ WhT,
                                                        const float* __restrict__ bias,
                                                        __half* __restrict__ hraw,
                                                        float* __restrict__ p2) {
    __shared__ float smem[8704];
    __half* wl = (__half*)smem;

    int t = threadIdx.x;

    #pragma unroll
    for (int i = 0; i < 8; ++i) {
        int cch = t + 256 * i;
        int n = cch >> 4;
        int ch = cch & 15;
        *(float4*)((char*)wl + n * 272 + ch * 16) =
            *(const float4*)((const char*)WhT + n * 256 + ch * 16);
    }

    int w = t >> 6;
    int lane = t & 63;
    int m = lane & 15;
    int quad = lane >> 4;
    int r0 = blockIdx.x * 64 + w * 16;
    int arow = r0 + m;

    half8 afrag[4];
    if (arow < NODES) {
        const char* ap = (const char*)(A + (size_t)arow * DIM);
        #pragma unroll
        for (int kt = 0; kt < 4; ++kt)
            afrag[kt] = *(const half8*)(ap + kt * 64 + quad * 16);
    } else {
        #pragma unroll
        for (int kt = 0; kt < 4; ++kt)
            #pragma unroll
            for (int j = 0; j < 8; ++j)
                afrag[kt][j] = (_Float16)0.0f;
    }

    floatx4 acc[8];
    floatx4 zf = {0.f, 0.f, 0.f, 0.f};
    #pragma unroll
    for (int ct = 0; ct < 8; ++ct) acc[ct] = zf;

    __syncthreads();

    #pragma unroll
    for (int kt = 0; kt < 4; ++kt) {
        #pragma unroll
        for (int ct = 0; ct < 8; ++ct) {
            half8 b = *(const half8*)((const char*)wl + (ct * 16 + m) * 272 + kt * 64 + quad * 16);
            acc[ct] = __builtin_amdgcn_mfma_f32_16x16x32_f16(afrag[kt], b, acc[ct], 0, 0, 0);
        }
    }

    __syncthreads();   // wl fully consumed; reuse as stats scratch

    float* ps = smem;
    int g = w * 4 + quad;
    #pragma unroll
    for (int ct = 0; ct < 8; ++ct) {
        int col = ct * 16 + m;
        float bb = bias[col];
        float cs = 0.f, cq = 0.f;
        #pragma unroll
        for (int reg = 0; reg < 4; ++reg) {
            int row = r0 + quad * 4 + reg;
            if (row < NODES) {
                float o = acc[ct][reg] + bb;
                hraw[(size_t)row * DIM + col] = __float2half(o);
                cs += o;
                cq += o * o;
            }
        }
        ps[g * 128 + col] = cs;
        ps[2048 + g * 128 + col] = cq;
    }
    __syncthreads();

    float* pslot = p2 + (blockIdx.x & 31) * 256;
    if (t < 128) {
        float s = 0.f;
        #pragma unroll
        for (int gg = 0; gg < 16; ++gg) s += ps[gg * 128 + t];
        atomicAdd(pslot + t, s);
    } else {
        int cc = t - 128;
        float s = 0.f;
        #pragma unroll
        for (int gg = 0; gg < 16; ++gg) s += ps[2048 + gg * 128 + cc];
        atomicAdd(pslot + 128 + cc, s);
    }
}

// ---------------- reduce p2 -> stats; re-zero p2 for next use ----------------
__global__ __launch_bounds__(256) void stats_s2_kernel(float* __restrict__ p2,
                                                       float* __restrict__ stats) {
    int t = threadIdx.x;
    float s = 0.f;
    #pragma unroll
    for (int b = 0; b < 32; ++b) s += p2[b * 256 + t];
    stats[t] = s;
    #pragma unroll
    for (int b = 0; b < 32; ++b) p2[b * 256 + t] = 0.f;
}

// ---------------- BN apply + ReLU (fp16 in) -> hs fp16 (scaled) ----------------
__global__ __launch_bounds__(256) void bn_relu_scale_kernel(const __half* __restrict__ hraw,
                                                            __half* __restrict__ hs,
                                                            const float* __restrict__ stats,
                                                            const float* __restrict__ g,
                                                            const float* __restrict__ be,
                                                            const float* __restrict__ dn_out) {
    int idx = blockIdx.x * 256 + threadIdx.x;   // over N*16
    if (idx >= NODES * 16) return;
    int row = idx >> 4;
    int c8 = (idx & 15) * 8;
    const float invN = 1.0f / NODES;
    H8 u;
    u.v = *(const half8*)((const char*)hraw + ((size_t)row * DIM + c8) * 2);
    float o[8];
    #pragma unroll
    for (int k = 0; k < 4; ++k) {
        float2 f = __half22float2(u.h2[k]);
        o[2 * k] = f.x;
        o[2 * k + 1] = f.y;
    }
    #pragma unroll
    for (int j = 0; j < 8; ++j) {
        int cj = c8 + j;
        float mu = stats[cj] * invN;
        float var = stats[DIM + cj] * invN - mu * mu;
        float w = g[cj] * rsqrtf(var + EPS_BN);
        o[j] = fmaxf(w * (o[j] - mu) + be[cj], 0.f);
    }
    H8 us;
    float sc = dn_out[row];
    #pragma unroll
    for (int k = 0; k < 4; ++k)
        us.h2[k] = __floats2half2_rn(o[2 * k] * sc, o[2 * k + 1] * sc);
    *(half8*)((char*)hs + ((size_t)row * DIM + c8) * 2) = us.v;
}

// ---------------- BN + residual (reconstructed hs*sdeg) + ReLU -> out fp32 ----------
__global__ __launch_bounds__(256) void bn_res_relu_kernel(const __half* __restrict__ hraw,
                                                          const __half* __restrict__ hs,
                                                          const float* __restrict__ sdeg,
                                                          float* __restrict__ out,
                                                          const float* __restrict__ stats,
                                                          const float* __restrict__ g,
                                                          const float* __restrict__ be) {
    int idx = blockIdx.x * 256 + threadIdx.x;   // over N*16
    if (idx >= NODES * 16) return;
    int row = idx >> 4;
    int c8 = (idx & 15) * 8;
    const float invN = 1.0f / NODES;
    float sd = sdeg[row];
    H8 u, ur;
    u.v = *(const half8*)((const char*)hraw + ((size_t)row * DIM + c8) * 2);
    ur.v = *(const half8*)((const char*)hs + ((size_t)row * DIM + c8) * 2);
    float o[8], r[8];
    #pragma unroll
    for (int k = 0; k < 4; ++k) {
        float2 f = __half22float2(u.h2[k]);
        float2 fr = __half22float2(ur.h2[k]);
        o[2 * k] = f.x; o[2 * k + 1] = f.y;
        r[2 * k] = fr.x * sd; r[2 * k + 1] = fr.y * sd;
    }
    #pragma unroll
    for (int j = 0; j < 8; ++j) {
        int cj = c8 + j;
        float mu = stats[cj] * invN;
        float var = stats[DIM + cj] * invN - mu * mu;
        float w = g[cj] * rsqrtf(var + EPS_BN);
        o[j] = fmaxf(w * (o[j] - mu) + be[cj] + r[j], 0.f);
    }
    float* op = out + (size_t)row * DIM + c8;
    float4 o0 = {o[0], o[1], o[2], o[3]};
    float4 o1 = {o[4], o[5], o[6], o[7]};
    *(float4*)op = o0;
    *(float4*)(op + 4) = o1;
}

extern "C" void kernel_launch(void* const* d_in, const int* in_sizes, int n_in,
                              void* d_out, int out_size, void* d_ws, size_t ws_size,
                              hipStream_t stream) {
    const float* x      = (const float*)d_in[0];
    const int*   src    = (const int*)d_in[1];
    const int*   dst    = (const int*)d_in[2];
    const float* W1     = (const float*)d_in[3];
    const float* b1     = (const float*)d_in[4];
    const float* gamma1 = (const float*)d_in[5];
    const float* beta1  = (const float*)d_in[6];
    const float* W2     = (const float*)d_in[7];
    const float* b2     = (const float*)d_in[8];
    const float* gamma2 = (const float*)d_in[9];
    const float* beta2  = (const float*)d_in[10];
    float* out = (float*)d_out;

    char* wsc = (char*)d_ws;
    int*   cnt_in   = (int*)wsc;                     wsc += NODES * 4;
    float* dn_out   = (float*)wsc;                   wsc += NODES * 4;
    float* sdeg     = (float*)wsc;                   wsc += NODES * 4;
    float* dn_in    = (float*)wsc;                   wsc += NODES * 4;
    int*   row_ptr  = (int*)wsc;                     wsc += (NODES + 1) * 4;
    int*   csr_src  = (int*)wsc;                     wsc += EDGES * 4;
    float* stats    = (float*)wsc;                   wsc += 2 * DIM * 4;
    int*   blk_sums = (int*)wsc;                     wsc += 64 * 4;
    __half* WhT1    = (__half*)wsc;                  wsc += DIM * DIM * 2;
    __half* WhT2    = (__half*)wsc;                  wsc += DIM * DIM * 2;
    float* p2       = (float*)wsc;                   wsc += 32 * 256 * 4;
    unsigned short* Psrc = (unsigned short*)wsc;     wsc += (size_t)NCH * NODES * 2;
    unsigned short* Pdst = (unsigned short*)wsc;     wsc += (size_t)NCH * NODES * 2;
    __half* hs      = (__half*)wsc;                  wsc += (size_t)NODES * DIM * 2;
    __half* agg     = (__half*)wsc;                  wsc += (size_t)NODES * DIM * 2;
    __half* hraw    = (__half*)wsc;                  wsc += (size_t)NODES * DIM * 2;

    const int T = 256;
    const int grid_pull = (NODES + 3) / 4;
    const int grid_e16  = (NODES * 16 + T - 1) / T;

    // graph prep — LDS atomics only
    hist_part_kernel<<<dim3(NR * NCH, 2), T, 0, stream>>>(src, dst, Psrc, Pdst);
    combine_kernel<<<(NODES + T - 1) / T, T, 0, stream>>>(Psrc, Pdst, cnt_in, dn_out, sdeg, dn_in);
    scan_p1_kernel<<<SCAN_NB, SCAN_B, 0, stream>>>(cnt_in, row_ptr, blk_sums);
    scan_p3_kernel<<<SCAN_NB, SCAN_B, 0, stream>>>(row_ptr, blk_sums);
    fill_kernel<<<NR * NCH, T, 0, stream>>>(src, dst, row_ptr, Pdst, csr_src);

    // weight conversion + p2 zero
    w2h_kernel<<<128, T, 0, stream>>>(W1, W2, WhT1, WhT2, p2);

    // layer 1
    prescale_kernel<<<grid_e16, T, 0, stream>>>(x, dn_out, hs);
    pull_kernel<<<grid_pull, T, 0, stream>>>(hs, row_ptr, csr_src, dn_in, agg);
    gemm_mfma_kernel<<<GEMM_NB, T, 0, stream>>>(agg, WhT1, b1, hraw, p2);
    stats_s2_kernel<<<1, T, 0, stream>>>(p2, stats);
    bn_relu_scale_kernel<<<grid_e16, T, 0, stream>>>(hraw, hs, stats, gamma1, beta1, dn_out);

    // layer 2
    pull_kernel<<<grid_pull, T, 0, stream>>>(hs, row_ptr, csr_src, dn_in, agg);
    gemm_mfma_kernel<<<GEMM_NB, T, 0, stream>>>(agg, WhT2, b2, hraw, p2);
    stats_s2_kernel<<<1, T, 0, stream>>>(p2, stats);
    bn_res_relu_kernel<<<grid_e16, T, 0, stream>>>(hraw, hs, sdeg, out, stats, gamma2, beta2);
}